// Round 5
// baseline (164.991 us; speedup 1.0000x reference)
//
#include <hip/hip_runtime.h>
#include <math.h>

typedef __attribute__((ext_vector_type(8))) short bf16x8;
typedef __attribute__((ext_vector_type(4))) float f32x4;

#define PI_F 3.14159265358979323846f

__device__ __forceinline__ unsigned short f2bf(float f) {
  unsigned int u = __float_as_uint(f);
  u += 0x7FFFu + ((u >> 16) & 1u);   // RNE to bf16
  return (unsigned short)(u >> 16);
}

__device__ __forceinline__ float bf2f(unsigned short u) {
  return __uint_as_float(((unsigned int)u) << 16);
}

__device__ __forceinline__ void async_ld16(const unsigned short* g, unsigned short* l) {
  __builtin_amdgcn_global_load_lds(
      (const __attribute__((address_space(1))) void*)g,
      (__attribute__((address_space(3))) void*)l,
      16, 0, 0);
}

// fast erf, A&S 7.1.26, |err| <= 1.5e-7 absolute
__device__ __forceinline__ float fast_erf(float x) {
  float a = fabsf(x);
  float t = 1.0f / fmaf(0.3275911f, a, 1.0f);
  float p = t * fmaf(t, fmaf(t, fmaf(t, fmaf(t, 1.061405429f, -1.453152027f),
                                     1.421413741f), -0.284496736f), 0.254829592f);
  float e = __expf(-a * a);
  float r = 1.0f - p * e;
  return copysignf(r, x);
}

__device__ __forceinline__ float fast_tanh(float a) {
  float e = __expf(2.0f * a);
  return 1.0f - 2.0f / (e + 1.0f);
}

// RX on stored basis: XOR-pair (lane-mask ML, register-mask MR); RX matrix symmetric.
template<int ML, int MR>
__device__ __forceinline__ void apply_rx(float re[4], float im[4], float c, float s) {
  float pr[4], pi[4];
  #pragma unroll
  for (int r = 0; r < 4; r++) {
    float vr = re[r ^ MR], vi = im[r ^ MR];
    if (ML) { vr = __shfl_xor(vr, ML, 64); vi = __shfl_xor(vi, ML, 64); }
    pr[r] = vr; pi[r] = vi;
  }
  #pragma unroll
  for (int r = 0; r < 4; r++) {
    re[r] = fmaf(c, re[r],  s * pi[r]);
    im[r] = fmaf(c, im[r], -s * pr[r]);
  }
}

// fold-reduce 8 values across 64 lanes: 10 shuffles. On exit v[0] of lane L holds
// the wave-sum of value w(L) = 4*(L&1) + (L&2) + ((L>>2)&1).
__device__ __forceinline__ void fold_reduce8(float v[8], int L) {
  #pragma unroll
  for (int step = 0; step < 3; step++) {
    int d = 1 << step;
    int half = 4 >> step;
    bool hi = (L & d) != 0;
    #pragma unroll
    for (int w = 0; w < half; w++) {
      float send = hi ? v[w] : v[w + half];
      float recv = __shfl_xor(send, d, 64);
      v[w] = (hi ? v[w + half] : v[w]) + recv;
    }
  }
  v[0] += __shfl_xor(v[0], 8, 64);
  v[0] += __shfl_xor(v[0], 16, 64);
  v[0] += __shfl_xor(v[0], 32, 64);
}

// ---------------- prep: adj->bf16, Wg->bf16, U-builder, x transpose+cvt --------
// blocks [0,1024): adj cvt; [1024,1088): Wg cvt; [1088,1152): U-builder;
// [1152,5248): transpose x (16,1024,256) -> xT (16,256,1024) bf16.
__global__ __launch_bounds__(256)
void prep_kernel(const float* __restrict__ adj, unsigned short* __restrict__ adj_bf,
                 const float* __restrict__ Wg, unsigned short* __restrict__ Wg_bf,
                 const float* __restrict__ qw, unsigned short* __restrict__ Uri,
                 const float* __restrict__ x, unsigned short* __restrict__ xT) {
  __shared__ float smem[1056];
  int bid = blockIdx.x, t = threadIdx.x;
  if (bid < 1024) {
    int i = bid * 256 + t;
    float4 v = ((const float4*)adj)[i];
    ushort4 o; o.x = f2bf(v.x); o.y = f2bf(v.y); o.z = f2bf(v.z); o.w = f2bf(v.w);
    ((ushort4*)adj_bf)[i] = o;
  } else if (bid < 1088) {
    int i = (bid - 1024) * 256 + t;
    float4 v = ((const float4*)Wg)[i];
    ushort4 o; o.x = f2bf(v.x); o.y = f2bf(v.y); o.z = f2bf(v.z); o.w = f2bf(v.w);
    ((ushort4*)Wg_bf)[i] = o;
  } else if (bid < 1152) {
    // U-builder: simulate entangler on basis k; self-contained gate table.
    // CNOT rings deferred; layer-2 RX masks = R^-1 e_w; output row n = R^2 s (logical).
    if (t < 16) { smem[t] = cosf(0.5f * qw[t]); smem[16 + t] = sinf(0.5f * qw[t]); }
    __syncthreads();
    int wv = t >> 6, L = t & 63;
    int k = (bid - 1088) * 4 + wv;
    float re[4], im[4];
    #pragma unroll
    for (int r = 0; r < 4; r++) { re[r] = (r * 64 + L == k) ? 1.f : 0.f; im[r] = 0.f; }
    // layer 1 RX (F = I)
    apply_rx<1, 0>(re, im, smem[0], smem[16]);
    apply_rx<2, 0>(re, im, smem[1], smem[17]);
    apply_rx<4, 0>(re, im, smem[2], smem[18]);
    apply_rx<8, 0>(re, im, smem[3], smem[19]);
    apply_rx<16, 0>(re, im, smem[4], smem[20]);
    apply_rx<32, 0>(re, im, smem[5], smem[21]);
    apply_rx<0, 1>(re, im, smem[6], smem[22]);
    apply_rx<0, 2>(re, im, smem[7], smem[23]);
    // layer 2 RX (F = R): masks R^-1 e_w
    apply_rx<3, 0>(re, im, smem[8], smem[24]);
    apply_rx<6, 0>(re, im, smem[9], smem[25]);
    apply_rx<12, 0>(re, im, smem[10], smem[26]);
    apply_rx<24, 0>(re, im, smem[11], smem[27]);
    apply_rx<48, 0>(re, im, smem[12], smem[28]);
    apply_rx<32, 1>(re, im, smem[13], smem[29]);
    apply_rx<0, 3>(re, im, smem[14], smem[30]);
    apply_rx<3, 2>(re, im, smem[15], smem[31]);
    const int M[8] = {0xAB, 0xFD, 0xFA, 0xF5, 0xEA, 0xD5, 0xAA, 0x55};
    #pragma unroll
    for (int r = 0; r < 4; r++) {
      int n = 0;
      #pragma unroll
      for (int w = 0; w < 8; w++) {
        int bit = (__popc(L & (M[w] & 63)) ^ __popc((r << 6) & M[w])) & 1;
        n |= bit << w;
      }
      Uri[(size_t)n * 256 + k] = f2bf(re[r]);
      Uri[(size_t)(256 + n) * 256 + k] = f2bf(im[r]);
    }
  } else {
    int tb = bid - 1152;
    int jt = tb & 31, ht = (tb >> 5) & 7, bb = tb >> 8;
    int tx = t & 31, ty = t >> 5;
    const float* xb = x + (size_t)bb * 1024 * 256;
    #pragma unroll
    for (int i = 0; i < 4; i++) {
      int j = jt * 32 + ty + i * 8;
      smem[(ty + i * 8) * 33 + tx] = xb[(size_t)j * 256 + ht * 32 + tx];
    }
    __syncthreads();
    unsigned short* xTb = xT + (size_t)bb * 256 * 1024;
    #pragma unroll
    for (int i = 0; i < 4; i++) {
      int h = ht * 32 + ty + i * 8;
      xTb[(size_t)h * 1024 + jt * 32 + tx] = f2bf(smem[tx * 33 + ty + i * 8]);
    }
  }
}

// ---------------- MFMA GEMM, C = A * Bt^T, tile 128(M) x 64(N) x 32(K) ----
// MODE 0: store bf16 C.  MODE 1: bias + GELU(erf), store bf16 C.
template<int MODE>
__global__ __launch_bounds__(256)
void gemm_bt_kernel(const unsigned short* __restrict__ A,
                    const unsigned short* __restrict__ Bt,
                    unsigned short* __restrict__ C,
                    const float* __restrict__ bias,
                    int K, int tilesM, int tilesN,
                    long long strideA, long long strideBt, long long strideC, int ldC) {
  __shared__ unsigned short As[128 * 32];
  __shared__ unsigned short Bs[64 * 32];
  int tiles = tilesM * tilesN;
  int b   = blockIdx.x / tiles;
  int rr  = blockIdx.x % tiles;
  int im  = rr / tilesN;
  int in_ = rr % tilesN;
  const unsigned short* Ab  = A  + (long long)b * strideA  + (long long)im * 128 * K;
  const unsigned short* Btb = Bt + (long long)b * strideBt + (long long)in_ * 64 * K;

  int t = threadIdx.x;
  int wv = t >> 6, lane = t & 63;
  int wm = wv >> 1, wn = wv & 1;
  int l15 = lane & 15, quad = lane >> 4;
  int row0 = t >> 2, cg = t & 3;

  f32x4 acc[4][2] = {};

  for (int kk = 0; kk < K; kk += 32) {
    __syncthreads();
    #pragma unroll
    for (int q = 0; q < 2; q++) {
      int row = row0 + q * 64;
      async_ld16(Ab + (long long)row * K + kk + cg * 8,
                 &As[(wv * 16 + q * 64) * 32]);
    }
    async_ld16(Btb + (long long)row0 * K + kk + cg * 8,
               &Bs[wv * 16 * 32]);
    __syncthreads();
    bf16x8 af[4], bfr[2];
    #pragma unroll
    for (int mt = 0; mt < 4; mt++)
      af[mt] = *(const bf16x8*)&As[(wm * 64 + mt * 16 + l15) * 32 + quad * 8];
    #pragma unroll
    for (int nt = 0; nt < 2; nt++)
      bfr[nt] = *(const bf16x8*)&Bs[(wn * 32 + nt * 16 + l15) * 32 + quad * 8];
    #pragma unroll
    for (int mt = 0; mt < 4; mt++)
      #pragma unroll
      for (int nt = 0; nt < 2; nt++)
        acc[mt][nt] = __builtin_amdgcn_mfma_f32_16x16x32_bf16(af[mt], bfr[nt], acc[mt][nt], 0, 0, 0);
  }

  unsigned short* Cb = C + (long long)b * strideC;
  int n0 = in_ * 64;
  #pragma unroll
  for (int mt = 0; mt < 4; mt++) {
    #pragma unroll
    for (int nt = 0; nt < 2; nt++) {
      int colg = n0 + wn * 32 + nt * 16 + l15;
      #pragma unroll
      for (int r = 0; r < 4; r++) {
        long long rowg = (long long)im * 128 + wm * 64 + mt * 16 + quad * 4 + r;
        float v = acc[mt][nt][r];
        if (MODE == 1) {
          v += bias[colg];
          v = 0.5f * v * (1.0f + fast_erf(v * 0.7071067811865475f));
        }
        Cb[rowg * ldC + colg] = f2bf(v);
      }
    }
  }
}

// ---------------- qgemm: fused P0-build + S = P0 x Uri^T + measurement + Wpost ----
// 512 threads (8 waves); M-tile 64 rows; N = 512 full width (wave wv -> cols wv*64..+63).
// Prologue: angles -> tanh -> RY product state straight from bf16 g into padded LDS.
// Uri rows already in LOGICAL basis -> measurement masks are plain e_w:
//   col c = wv*64 + nt*16 + l15 ; n = c&255 ; n bits: 0-3 = l15, 4-5 = nt, 6-7 = wv&3.
__global__ __launch_bounds__(512)
void qgemm_kernel(const unsigned short* __restrict__ g,
                  const unsigned short* __restrict__ Uri,
                  const float* __restrict__ Wpre, const float* __restrict__ bpre,
                  const float* __restrict__ Wpost, const float* __restrict__ bpost,
                  float* __restrict__ out) {
  __shared__ unsigned short P0s[64 * 264];   // 33 KB, padded rows (264) -> conflict-free A reads
  __shared__ unsigned short Bs[512 * 32];    // 32 KB
  __shared__ float sWpre[2048];              // 8 KB  [w][h]
  __shared__ float sWpostT[2048];            // 8 KB  [w][h]
  __shared__ float sBpost[256];              // 1 KB
  __shared__ float zpart[8 * 64 * 8];        // 16 KB [wv][row][w]
  __shared__ float zfin[64 * 8];             // 2 KB  [row][w]

  int t = threadIdx.x;
  int wv = t >> 6, lane = t & 63;
  int l15 = lane & 15, quad = lane >> 4;

  for (int i = t; i < 2048; i += 512) {
    sWpre[i] = Wpre[i];
    sWpostT[i] = Wpost[(i & 255) * 8 + (i >> 8)];
  }
  if (t < 256) sBpost[t] = bpost[t];

  // preload this wave's 8 g-rows (lane covers cols 4L..4L+3)
  const unsigned short* gb = g + (size_t)blockIdx.x * 64 * 256;
  ushort4 gu[8];
  #pragma unroll
  for (int rr = 0; rr < 8; rr++)
    gu[rr] = *(const ushort4*)(gb + (size_t)(wv * 8 + rr) * 256 + 4 * lane);

  __syncthreads();   // sWpre ready

  // ---- prologue: build P0 rows wv*8..wv*8+7 ----
  for (int rr = 0; rr < 8; rr++) {
    int row = wv * 8 + rr;
    float g0 = bf2f(gu[rr].x), g1 = bf2f(gu[rr].y), g2 = bf2f(gu[rr].z), g3 = bf2f(gu[rr].w);
    float ang[8];
    #pragma unroll
    for (int w = 0; w < 8; w++) {
      float4 wp = *(const float4*)&sWpre[w * 256 + 4 * lane];
      float a = g0 * wp.x;
      a = fmaf(g1, wp.y, a);
      a = fmaf(g2, wp.z, a);
      a = fmaf(g3, wp.w, a);
      ang[w] = a;
    }
    fold_reduce8(ang, lane);
    float angf[8];
    #pragma unroll
    for (int w = 0; w < 8; w++) {
      int src = ((w >> 2) & 1) | (w & 2) | ((w & 1) << 2);
      angf[w] = __shfl(ang[0], src, 64);
    }
    float cw[8], sw[8];
    #pragma unroll
    for (int w = 0; w < 8; w++) {
      float th = (0.5f * PI_F) * fast_tanh(angf[w] + bpre[w]);
      cw[w] = __cosf(th); sw[w] = __sinf(th);
    }
    // amp index n = 4*lane + j : bits 0,1 = j ; bits 2..7 = lane bits 0..5
    float pl = 1.f;
    #pragma unroll
    for (int bbit = 0; bbit < 6; bbit++) pl *= ((lane >> bbit) & 1) ? sw[bbit + 2] : cw[bbit + 2];
    ushort4 o;
    o.x = f2bf(pl * cw[0] * cw[1]);
    o.y = f2bf(pl * sw[0] * cw[1]);
    o.z = f2bf(pl * cw[0] * sw[1]);
    o.w = f2bf(pl * sw[0] * sw[1]);
    *(ushort4*)&P0s[row * 264 + 4 * lane] = o;
  }

  // ---- main loop: S = P0 x Uri^T ----
  f32x4 acc[4][4] = {};
  for (int kk = 0; kk < 256; kk += 32) {
    __syncthreads();   // P0s complete (first iter) / Bs consumed (later iters)
    #pragma unroll
    for (int rd = 0; rd < 4; rd++) {
      int ch = rd * 512 + t;
      async_ld16(Uri + (size_t)(ch >> 2) * 256 + kk + (ch & 3) * 8,
                 &Bs[(rd * 512 + wv * 64) * 8]);
    }
    __syncthreads();
    bf16x8 af[4], bfr[4];
    #pragma unroll
    for (int mt = 0; mt < 4; mt++)
      af[mt] = *(const bf16x8*)&P0s[(mt * 16 + l15) * 264 + kk + quad * 8];
    #pragma unroll
    for (int nt = 0; nt < 4; nt++)
      bfr[nt] = *(const bf16x8*)&Bs[(wv * 64 + nt * 16 + l15) * 32 + quad * 8];
    #pragma unroll
    for (int mt = 0; mt < 4; mt++)
      #pragma unroll
      for (int nt = 0; nt < 4; nt++)
        acc[mt][nt] = __builtin_amdgcn_mfma_f32_16x16x32_bf16(af[mt], bfr[nt], acc[mt][nt], 0, 0, 0);
  }

  // ---- measurement: z_w[row] = sum_n (-1)^{n bit w} (Sre^2 + Sim^2) ----
  #pragma unroll
  for (int mt = 0; mt < 4; mt++) {
    #pragma unroll
    for (int r = 0; r < 4; r++) {
      float v0 = acc[mt][0][r] * acc[mt][0][r];
      float v1 = acc[mt][1][r] * acc[mt][1][r];
      float v2 = acc[mt][2][r] * acc[mt][2][r];
      float v3 = acc[mt][3][r] * acc[mt][3][r];
      float W0 = (v0 + v1) + (v2 + v3);
      float W1 = (v0 - v1) + (v2 - v3);   // sign on n bit4 (nt bit0)
      float W2 = (v0 + v1) - (v2 + v3);   // sign on n bit5 (nt bit1)
      float P[8];
      P[0] = (l15 & 1) ? -W0 : W0;
      P[1] = (l15 & 2) ? -W0 : W0;
      P[2] = (l15 & 4) ? -W0 : W0;
      P[3] = (l15 & 8) ? -W0 : W0;
      P[4] = W1;
      P[5] = W2;
      P[6] = (wv & 1) ? -W0 : W0;
      P[7] = (wv & 2) ? -W0 : W0;
      #pragma unroll
      for (int step = 0; step < 3; step++) {
        int d = 1 << step;
        int half = 4 >> step;
        bool hi = (lane & d) != 0;
        #pragma unroll
        for (int w = 0; w < half; w++) {
          float send = hi ? P[w] : P[w + half];
          float recv = __shfl_xor(send, d, 64);
          P[w] = (hi ? P[w + half] : P[w]) + recv;
        }
      }
      P[0] += __shfl_xor(P[0], 8, 64);
      int row = mt * 16 + quad * 4 + r;
      int widx = 4 * (lane & 1) + (lane & 2) + ((lane >> 2) & 1);
      if (l15 < 8) zpart[wv * 512 + row * 8 + widx] = P[0];
    }
  }
  __syncthreads();
  {
    float ssum = zpart[t];
    #pragma unroll
    for (int w2 = 1; w2 < 8; w2++) ssum += zpart[w2 * 512 + t];
    zfin[t] = ssum;
  }
  __syncthreads();

  // ---- projection: wave wv -> rows wv*8..+7; lane covers cols 4L..4L+3 ----
  float4 wp[8];
  #pragma unroll
  for (int w = 0; w < 8; w++) wp[w] = *(const float4*)&sWpostT[w * 256 + 4 * lane];
  float4 bp = *(const float4*)&sBpost[4 * lane];
  #pragma unroll
  for (int rr = 0; rr < 8; rr++) {
    int row = wv * 8 + rr;
    float4 z0 = *(const float4*)&zfin[row * 8];
    float4 z1 = *(const float4*)&zfin[row * 8 + 4];
    float4 v = bp;
    v.x = fmaf(z0.x, wp[0].x, v.x); v.y = fmaf(z0.x, wp[0].y, v.y);
    v.z = fmaf(z0.x, wp[0].z, v.z); v.w = fmaf(z0.x, wp[0].w, v.w);
    v.x = fmaf(z0.y, wp[1].x, v.x); v.y = fmaf(z0.y, wp[1].y, v.y);
    v.z = fmaf(z0.y, wp[1].z, v.z); v.w = fmaf(z0.y, wp[1].w, v.w);
    v.x = fmaf(z0.z, wp[2].x, v.x); v.y = fmaf(z0.z, wp[2].y, v.y);
    v.z = fmaf(z0.z, wp[2].z, v.z); v.w = fmaf(z0.z, wp[2].w, v.w);
    v.x = fmaf(z0.w, wp[3].x, v.x); v.y = fmaf(z0.w, wp[3].y, v.y);
    v.z = fmaf(z0.w, wp[3].z, v.z); v.w = fmaf(z0.w, wp[3].w, v.w);
    v.x = fmaf(z1.x, wp[4].x, v.x); v.y = fmaf(z1.x, wp[4].y, v.y);
    v.z = fmaf(z1.x, wp[4].z, v.z); v.w = fmaf(z1.x, wp[4].w, v.w);
    v.x = fmaf(z1.y, wp[5].x, v.x); v.y = fmaf(z1.y, wp[5].y, v.y);
    v.z = fmaf(z1.y, wp[5].z, v.z); v.w = fmaf(z1.y, wp[5].w, v.w);
    v.x = fmaf(z1.z, wp[6].x, v.x); v.y = fmaf(z1.z, wp[6].y, v.y);
    v.z = fmaf(z1.z, wp[6].z, v.z); v.w = fmaf(z1.z, wp[6].w, v.w);
    v.x = fmaf(z1.w, wp[7].x, v.x); v.y = fmaf(z1.w, wp[7].y, v.y);
    v.z = fmaf(z1.w, wp[7].z, v.z); v.w = fmaf(z1.w, wp[7].w, v.w);
    ((float4*)(out + ((size_t)blockIdx.x * 64 + row) * 256))[lane] = v;
  }
}

// ---------------- host launch ----------------
extern "C" void kernel_launch(void* const* d_in, const int* in_sizes, int n_in,
                              void* d_out, int out_size, void* d_ws, size_t ws_size,
                              hipStream_t stream) {
  const float* x     = (const float*)d_in[0];  // (16,1024,256)
  const float* adj   = (const float*)d_in[1];  // (1024,1024)
  const float* Wg    = (const float*)d_in[2];  // (256,256)
  const float* bg    = (const float*)d_in[3];  // (256,)
  const float* Wpre  = (const float*)d_in[4];  // (8,256)
  const float* bpre  = (const float*)d_in[5];  // (8,)
  const float* qw    = (const float*)d_in[6];  // (2,8)
  const float* Wpost = (const float*)d_in[7];  // (256,8)
  const float* bpost = (const float*)d_in[8];  // (256,)
  float* out = (float*)d_out;                  // (16,1024,256)

  char* ws = (char*)d_ws;
  unsigned short* adj_bf  = (unsigned short*)(ws + 0);          // 2 MiB
  unsigned short* Wg_bf   = (unsigned short*)(ws + 2097152);    // 128 KiB
  unsigned short* xagg_bf = (unsigned short*)(ws + 2228224);    // 8 MiB  (16384 x 256)
  unsigned short* xT_bf   = (unsigned short*)(ws + 10616832);   // 8 MiB  (16 x 256 x 1024)
  unsigned short* g_bf    = (unsigned short*)(ws + 19005440);   // 8 MiB  (16384 x 256)
  unsigned short* Uri     = (unsigned short*)(ws + 27394048);   // 256 KiB (512 x 256)

  // 1) prep: adj/Wg cvt + U-builder + x transpose
  prep_kernel<<<5248, 256, 0, stream>>>(adj, adj_bf, Wg, Wg_bf, qw, Uri, x, xT_bf);

  // 2) x_agg[b] = adj @ x[b] -> bf16
  gemm_bt_kernel<0><<<512, 256, 0, stream>>>(adj_bf, xT_bf, xagg_bf, nullptr,
                                             1024, 8, 4,
                                             0LL, 262144LL, 262144LL, 256);

  // 3) g = gelu(x_agg @ Wg^T + bg) -> bf16
  gemm_bt_kernel<1><<<512, 256, 0, stream>>>(xagg_bf, Wg_bf, g_bf, bg,
                                             256, 128, 4,
                                             0LL, 0LL, 0LL, 256);

  // 4) fused P0-build + S-GEMM + measurement + Wpost projection
  qgemm_kernel<<<256, 512, 0, stream>>>(g_bf, Uri, Wpre, bpre, Wpost, bpost, out);
}

// Round 6
// 157.926 us; speedup vs baseline: 1.0447x; 1.0447x over previous
//
#include <hip/hip_runtime.h>
#include <math.h>

typedef __attribute__((ext_vector_type(8))) short bf16x8;
typedef __attribute__((ext_vector_type(4))) float f32x4;

#define PI_F 3.14159265358979323846f

__device__ __forceinline__ unsigned short f2bf(float f) {
  unsigned int u = __float_as_uint(f);
  u += 0x7FFFu + ((u >> 16) & 1u);   // RNE to bf16
  return (unsigned short)(u >> 16);
}

__device__ __forceinline__ float bf2f(unsigned short u) {
  return __uint_as_float(((unsigned int)u) << 16);
}

__device__ __forceinline__ void async_ld16(const unsigned short* g, unsigned short* l) {
  __builtin_amdgcn_global_load_lds(
      (const __attribute__((address_space(1))) void*)g,
      (__attribute__((address_space(3))) void*)l,
      16, 0, 0);
}

// fast erf, A&S 7.1.26, |err| <= 1.5e-7 absolute
__device__ __forceinline__ float fast_erf(float x) {
  float a = fabsf(x);
  float t = 1.0f / fmaf(0.3275911f, a, 1.0f);
  float p = t * fmaf(t, fmaf(t, fmaf(t, fmaf(t, 1.061405429f, -1.453152027f),
                                     1.421413741f), -0.284496736f), 0.254829592f);
  float e = __expf(-a * a);
  float r = 1.0f - p * e;
  return copysignf(r, x);
}

__device__ __forceinline__ float fast_tanh(float a) {
  float e = __expf(2.0f * a);
  return 1.0f - 2.0f / (e + 1.0f);
}

// RX on stored basis: XOR-pair (lane-mask ML, register-mask MR); RX matrix symmetric.
template<int ML, int MR>
__device__ __forceinline__ void apply_rx(float re[4], float im[4], float c, float s) {
  float pr[4], pi[4];
  #pragma unroll
  for (int r = 0; r < 4; r++) {
    float vr = re[r ^ MR], vi = im[r ^ MR];
    if (ML) { vr = __shfl_xor(vr, ML, 64); vi = __shfl_xor(vi, ML, 64); }
    pr[r] = vr; pi[r] = vi;
  }
  #pragma unroll
  for (int r = 0; r < 4; r++) {
    re[r] = fmaf(c, re[r],  s * pi[r]);
    im[r] = fmaf(c, im[r], -s * pr[r]);
  }
}

// fold-reduce 8 values across 64 lanes: 10 shuffles. On exit v[0] of lane L holds
// the wave-sum of value w(L) = 4*(L&1) + (L&2) + ((L>>2)&1).
__device__ __forceinline__ void fold_reduce8(float v[8], int L) {
  #pragma unroll
  for (int step = 0; step < 3; step++) {
    int d = 1 << step;
    int half = 4 >> step;
    bool hi = (L & d) != 0;
    #pragma unroll
    for (int w = 0; w < half; w++) {
      float send = hi ? v[w] : v[w + half];
      float recv = __shfl_xor(send, d, 64);
      v[w] = (hi ? v[w + half] : v[w]) + recv;
    }
  }
  v[0] += __shfl_xor(v[0], 8, 64);
  v[0] += __shfl_xor(v[0], 16, 64);
  v[0] += __shfl_xor(v[0], 32, 64);
}

// ---------------- prep: adj->bf16, Wg->bf16, U-builder, x transpose+cvt --------
// blocks [0,1024): adj cvt; [1024,1088): Wg cvt; [1088,1152): U-builder;
// [1152,5248): transpose x (16,1024,256) -> xT (16,256,1024) bf16.
__global__ __launch_bounds__(256)
void prep_kernel(const float* __restrict__ adj, unsigned short* __restrict__ adj_bf,
                 const float* __restrict__ Wg, unsigned short* __restrict__ Wg_bf,
                 const float* __restrict__ qw, unsigned short* __restrict__ Uri,
                 const float* __restrict__ x, unsigned short* __restrict__ xT) {
  __shared__ float smem[1056];
  int bid = blockIdx.x, t = threadIdx.x;
  if (bid < 1024) {
    int i = bid * 256 + t;
    float4 v = ((const float4*)adj)[i];
    ushort4 o; o.x = f2bf(v.x); o.y = f2bf(v.y); o.z = f2bf(v.z); o.w = f2bf(v.w);
    ((ushort4*)adj_bf)[i] = o;
  } else if (bid < 1088) {
    int i = (bid - 1024) * 256 + t;
    float4 v = ((const float4*)Wg)[i];
    ushort4 o; o.x = f2bf(v.x); o.y = f2bf(v.y); o.z = f2bf(v.z); o.w = f2bf(v.w);
    ((ushort4*)Wg_bf)[i] = o;
  } else if (bid < 1152) {
    // U-builder: simulate entangler on basis k; self-contained gate table.
    // CNOT rings deferred; layer-2 RX masks = R^-1 e_w; output row n = R^2 s (logical).
    if (t < 16) { smem[t] = cosf(0.5f * qw[t]); smem[16 + t] = sinf(0.5f * qw[t]); }
    __syncthreads();
    int wv = t >> 6, L = t & 63;
    int k = (bid - 1088) * 4 + wv;
    float re[4], im[4];
    #pragma unroll
    for (int r = 0; r < 4; r++) { re[r] = (r * 64 + L == k) ? 1.f : 0.f; im[r] = 0.f; }
    // layer 1 RX (F = I)
    apply_rx<1, 0>(re, im, smem[0], smem[16]);
    apply_rx<2, 0>(re, im, smem[1], smem[17]);
    apply_rx<4, 0>(re, im, smem[2], smem[18]);
    apply_rx<8, 0>(re, im, smem[3], smem[19]);
    apply_rx<16, 0>(re, im, smem[4], smem[20]);
    apply_rx<32, 0>(re, im, smem[5], smem[21]);
    apply_rx<0, 1>(re, im, smem[6], smem[22]);
    apply_rx<0, 2>(re, im, smem[7], smem[23]);
    // layer 2 RX (F = R): masks R^-1 e_w
    apply_rx<3, 0>(re, im, smem[8], smem[24]);
    apply_rx<6, 0>(re, im, smem[9], smem[25]);
    apply_rx<12, 0>(re, im, smem[10], smem[26]);
    apply_rx<24, 0>(re, im, smem[11], smem[27]);
    apply_rx<48, 0>(re, im, smem[12], smem[28]);
    apply_rx<32, 1>(re, im, smem[13], smem[29]);
    apply_rx<0, 3>(re, im, smem[14], smem[30]);
    apply_rx<3, 2>(re, im, smem[15], smem[31]);
    const int M[8] = {0xAB, 0xFD, 0xFA, 0xF5, 0xEA, 0xD5, 0xAA, 0x55};
    #pragma unroll
    for (int r = 0; r < 4; r++) {
      int n = 0;
      #pragma unroll
      for (int w = 0; w < 8; w++) {
        int bit = (__popc(L & (M[w] & 63)) ^ __popc((r << 6) & M[w])) & 1;
        n |= bit << w;
      }
      Uri[(size_t)n * 256 + k] = f2bf(re[r]);
      Uri[(size_t)(256 + n) * 256 + k] = f2bf(im[r]);
    }
  } else {
    int tb = bid - 1152;
    int jt = tb & 31, ht = (tb >> 5) & 7, bb = tb >> 8;
    int tx = t & 31, ty = t >> 5;
    const float* xb = x + (size_t)bb * 1024 * 256;
    #pragma unroll
    for (int i = 0; i < 4; i++) {
      int j = jt * 32 + ty + i * 8;
      smem[(ty + i * 8) * 33 + tx] = xb[(size_t)j * 256 + ht * 32 + tx];
    }
    __syncthreads();
    unsigned short* xTb = xT + (size_t)bb * 256 * 1024;
    #pragma unroll
    for (int i = 0; i < 4; i++) {
      int h = ht * 32 + ty + i * 8;
      xTb[(size_t)h * 1024 + jt * 32 + tx] = f2bf(smem[tx * 33 + ty + i * 8]);
    }
  }
}

// ---------------- MFMA GEMM, C = A * Bt^T, tile 128(M) x 64(N) x 32(K) ----
// MODE 0: store bf16 C.  MODE 1: bias + GELU(erf), store bf16 C.
template<int MODE>
__global__ __launch_bounds__(256)
void gemm_bt_kernel(const unsigned short* __restrict__ A,
                    const unsigned short* __restrict__ Bt,
                    unsigned short* __restrict__ C,
                    const float* __restrict__ bias,
                    int K, int tilesM, int tilesN,
                    long long strideA, long long strideBt, long long strideC, int ldC) {
  __shared__ unsigned short As[128 * 32];
  __shared__ unsigned short Bs[64 * 32];
  int tiles = tilesM * tilesN;
  int b   = blockIdx.x / tiles;
  int rr  = blockIdx.x % tiles;
  int im  = rr / tilesN;
  int in_ = rr % tilesN;
  const unsigned short* Ab  = A  + (long long)b * strideA  + (long long)im * 128 * K;
  const unsigned short* Btb = Bt + (long long)b * strideBt + (long long)in_ * 64 * K;

  int t = threadIdx.x;
  int wv = t >> 6, lane = t & 63;
  int wm = wv >> 1, wn = wv & 1;
  int l15 = lane & 15, quad = lane >> 4;
  int row0 = t >> 2, cg = t & 3;

  f32x4 acc[4][2] = {};

  for (int kk = 0; kk < K; kk += 32) {
    __syncthreads();
    #pragma unroll
    for (int q = 0; q < 2; q++) {
      int row = row0 + q * 64;
      async_ld16(Ab + (long long)row * K + kk + cg * 8,
                 &As[(wv * 16 + q * 64) * 32]);
    }
    async_ld16(Btb + (long long)row0 * K + kk + cg * 8,
               &Bs[wv * 16 * 32]);
    __syncthreads();
    bf16x8 af[4], bfr[2];
    #pragma unroll
    for (int mt = 0; mt < 4; mt++)
      af[mt] = *(const bf16x8*)&As[(wm * 64 + mt * 16 + l15) * 32 + quad * 8];
    #pragma unroll
    for (int nt = 0; nt < 2; nt++)
      bfr[nt] = *(const bf16x8*)&Bs[(wn * 32 + nt * 16 + l15) * 32 + quad * 8];
    #pragma unroll
    for (int mt = 0; mt < 4; mt++)
      #pragma unroll
      for (int nt = 0; nt < 2; nt++)
        acc[mt][nt] = __builtin_amdgcn_mfma_f32_16x16x32_bf16(af[mt], bfr[nt], acc[mt][nt], 0, 0, 0);
  }

  unsigned short* Cb = C + (long long)b * strideC;
  int n0 = in_ * 64;
  #pragma unroll
  for (int mt = 0; mt < 4; mt++) {
    #pragma unroll
    for (int nt = 0; nt < 2; nt++) {
      int colg = n0 + wn * 32 + nt * 16 + l15;
      #pragma unroll
      for (int r = 0; r < 4; r++) {
        long long rowg = (long long)im * 128 + wm * 64 + mt * 16 + quad * 4 + r;
        float v = acc[mt][nt][r];
        if (MODE == 1) {
          v += bias[colg];
          v = 0.5f * v * (1.0f + fast_erf(v * 0.7071067811865475f));
        }
        Cb[rowg * ldC + colg] = f2bf(v);
      }
    }
  }
}

// ---------------- qgemm: fused P0-build + S = P0 x Uri^T + measurement + Wpost ----
// 512 threads (8 waves); M-tile 32; grid 512 (2 blocks/CU -> prologue/K-loop overlap).
// Wave wv owns S-cols wv*64..wv*64+63 (N=512 full). B-frags read DIRECTLY from
// global (Uri L2-resident) -> no Bs, no barriers in the K-loop.
// P0s layout [kb][row][32] (m97-style, row stride 32 shorts) -> conflict-free b128.
// col c = wv*64 + nt*16 + l15 ; n = c & 255 ; n bits: 0-3 = l15, 4-5 = nt, 6-7 = wv&3.
__global__ __launch_bounds__(512)
void qgemm_kernel(const unsigned short* __restrict__ g,
                  const unsigned short* __restrict__ Uri,
                  const float* __restrict__ Wpre, const float* __restrict__ bpre,
                  const float* __restrict__ Wpost, const float* __restrict__ bpost,
                  float* __restrict__ out) {
  __shared__ unsigned short P0s[8 * 32 * 32];  // 16 KB, [kb][row][k%32]
  __shared__ float sWpre[2048];                // 8 KB  [w][h]
  __shared__ float sWpostT[2048];              // 8 KB  [w][h]
  __shared__ float sBpost[256];                // 1 KB
  __shared__ float zpart[8 * 32 * 8];          // 8 KB  [wv][row][w]
  __shared__ float zfin[32 * 8];               // 1 KB  [row][w]

  int t = threadIdx.x;
  int wv = t >> 6, lane = t & 63;
  int l15 = lane & 15, quad = lane >> 4;

  for (int i = t; i < 2048; i += 512) {
    sWpre[i] = Wpre[i];
    sWpostT[i] = Wpost[(i & 255) * 8 + (i >> 8)];
  }
  if (t < 256) sBpost[t] = bpost[t];

  // preload this wave's 4 g-rows (lane covers cols 4L..4L+3)
  const unsigned short* gb = g + (size_t)blockIdx.x * 32 * 256;
  ushort4 gu[4];
  #pragma unroll
  for (int rr = 0; rr < 4; rr++)
    gu[rr] = *(const ushort4*)(gb + (size_t)(wv * 4 + rr) * 256 + 4 * lane);

  __syncthreads();   // sWpre ready

  // ---- prologue: build P0 rows wv*4..wv*4+3 ----
  #pragma unroll
  for (int rr = 0; rr < 4; rr++) {
    int row = wv * 4 + rr;
    float g0 = bf2f(gu[rr].x), g1 = bf2f(gu[rr].y), g2 = bf2f(gu[rr].z), g3 = bf2f(gu[rr].w);
    float ang[8];
    #pragma unroll
    for (int w = 0; w < 8; w++) {
      float4 wp = *(const float4*)&sWpre[w * 256 + 4 * lane];
      float a = g0 * wp.x;
      a = fmaf(g1, wp.y, a);
      a = fmaf(g2, wp.z, a);
      a = fmaf(g3, wp.w, a);
      ang[w] = a;
    }
    fold_reduce8(ang, lane);
    float angf[8];
    #pragma unroll
    for (int w = 0; w < 8; w++) {
      int src = ((w >> 2) & 1) | (w & 2) | ((w & 1) << 2);
      angf[w] = __shfl(ang[0], src, 64);
    }
    float cw[8], sw[8];
    #pragma unroll
    for (int w = 0; w < 8; w++) {
      float th = (0.5f * PI_F) * fast_tanh(angf[w] + bpre[w]);
      cw[w] = __cosf(th); sw[w] = __sinf(th);
    }
    // amp index n = 4*lane + j : bits 0,1 = j ; bits 2..7 = lane bits 0..5
    float pl = 1.f;
    #pragma unroll
    for (int bbit = 0; bbit < 6; bbit++) pl *= ((lane >> bbit) & 1) ? sw[bbit + 2] : cw[bbit + 2];
    ushort4 o;
    o.x = f2bf(pl * cw[0] * cw[1]);
    o.y = f2bf(pl * sw[0] * cw[1]);
    o.z = f2bf(pl * cw[0] * sw[1]);
    o.w = f2bf(pl * sw[0] * sw[1]);
    // k-col 4*lane -> panel kb = lane>>3, offset 4*(lane&7)
    *(ushort4*)&P0s[(lane >> 3) * 1024 + row * 32 + 4 * (lane & 7)] = o;
  }
  __syncthreads();   // P0s complete

  // ---- K-loop: no barriers; B-frags straight from global (L2) ----
  f32x4 acc[2][4] = {};
  #pragma unroll
  for (int kk = 0; kk < 256; kk += 32) {
    bf16x8 af[2], bfr[4];
    #pragma unroll
    for (int mt = 0; mt < 2; mt++)
      af[mt] = *(const bf16x8*)&P0s[(kk >> 5) * 1024 + (mt * 16 + l15) * 32 + quad * 8];
    #pragma unroll
    for (int nt = 0; nt < 4; nt++)
      bfr[nt] = *(const bf16x8*)(Uri + (size_t)(wv * 64 + nt * 16 + l15) * 256 + kk + quad * 8);
    #pragma unroll
    for (int mt = 0; mt < 2; mt++)
      #pragma unroll
      for (int nt = 0; nt < 4; nt++)
        acc[mt][nt] = __builtin_amdgcn_mfma_f32_16x16x32_bf16(af[mt], bfr[nt], acc[mt][nt], 0, 0, 0);
  }

  // ---- measurement: z_w[row] = sum_n (-1)^{n bit w} (Sre^2 + Sim^2) ----
  #pragma unroll
  for (int mt = 0; mt < 2; mt++) {
    #pragma unroll
    for (int r = 0; r < 4; r++) {
      float v0 = acc[mt][0][r] * acc[mt][0][r];
      float v1 = acc[mt][1][r] * acc[mt][1][r];
      float v2 = acc[mt][2][r] * acc[mt][2][r];
      float v3 = acc[mt][3][r] * acc[mt][3][r];
      float W0 = (v0 + v1) + (v2 + v3);
      float W1 = (v0 - v1) + (v2 - v3);   // sign on n bit4 (nt bit0)
      float W2 = (v0 + v1) - (v2 + v3);   // sign on n bit5 (nt bit1)
      float P[8];
      P[0] = (l15 & 1) ? -W0 : W0;
      P[1] = (l15 & 2) ? -W0 : W0;
      P[2] = (l15 & 4) ? -W0 : W0;
      P[3] = (l15 & 8) ? -W0 : W0;
      P[4] = W1;
      P[5] = W2;
      P[6] = (wv & 1) ? -W0 : W0;
      P[7] = (wv & 2) ? -W0 : W0;
      #pragma unroll
      for (int step = 0; step < 3; step++) {
        int d = 1 << step;
        int half = 4 >> step;
        bool hi = (lane & d) != 0;
        #pragma unroll
        for (int w = 0; w < half; w++) {
          float send = hi ? P[w] : P[w + half];
          float recv = __shfl_xor(send, d, 64);
          P[w] = (hi ? P[w + half] : P[w]) + recv;
        }
      }
      P[0] += __shfl_xor(P[0], 8, 64);
      int row = mt * 16 + quad * 4 + r;
      int widx = 4 * (lane & 1) + (lane & 2) + ((lane >> 2) & 1);
      if (l15 < 8) zpart[wv * 256 + row * 8 + widx] = P[0];
    }
  }
  __syncthreads();
  if (t < 256) {
    float ssum = zpart[t];
    #pragma unroll
    for (int w2 = 1; w2 < 8; w2++) ssum += zpart[w2 * 256 + t];
    zfin[t] = ssum;
  }
  __syncthreads();

  // ---- projection: wave wv -> rows wv*4..+3; lane covers cols 4L..4L+3 ----
  float4 wp[8];
  #pragma unroll
  for (int w = 0; w < 8; w++) wp[w] = *(const float4*)&sWpostT[w * 256 + 4 * lane];
  float4 bp = *(const float4*)&sBpost[4 * lane];
  #pragma unroll
  for (int rr = 0; rr < 4; rr++) {
    int row = wv * 4 + rr;
    float4 z0 = *(const float4*)&zfin[row * 8];
    float4 z1 = *(const float4*)&zfin[row * 8 + 4];
    float4 v = bp;
    v.x = fmaf(z0.x, wp[0].x, v.x); v.y = fmaf(z0.x, wp[0].y, v.y);
    v.z = fmaf(z0.x, wp[0].z, v.z); v.w = fmaf(z0.x, wp[0].w, v.w);
    v.x = fmaf(z0.y, wp[1].x, v.x); v.y = fmaf(z0.y, wp[1].y, v.y);
    v.z = fmaf(z0.y, wp[1].z, v.z); v.w = fmaf(z0.y, wp[1].w, v.w);
    v.x = fmaf(z0.z, wp[2].x, v.x); v.y = fmaf(z0.z, wp[2].y, v.y);
    v.z = fmaf(z0.z, wp[2].z, v.z); v.w = fmaf(z0.z, wp[2].w, v.w);
    v.x = fmaf(z0.w, wp[3].x, v.x); v.y = fmaf(z0.w, wp[3].y, v.y);
    v.z = fmaf(z0.w, wp[3].z, v.z); v.w = fmaf(z0.w, wp[3].w, v.w);
    v.x = fmaf(z1.x, wp[4].x, v.x); v.y = fmaf(z1.x, wp[4].y, v.y);
    v.z = fmaf(z1.x, wp[4].z, v.z); v.w = fmaf(z1.x, wp[4].w, v.w);
    v.x = fmaf(z1.y, wp[5].x, v.x); v.y = fmaf(z1.y, wp[5].y, v.y);
    v.z = fmaf(z1.y, wp[5].z, v.z); v.w = fmaf(z1.y, wp[5].w, v.w);
    v.x = fmaf(z1.z, wp[6].x, v.x); v.y = fmaf(z1.z, wp[6].y, v.y);
    v.z = fmaf(z1.z, wp[6].z, v.z); v.w = fmaf(z1.z, wp[6].w, v.w);
    v.x = fmaf(z1.w, wp[7].x, v.x); v.y = fmaf(z1.w, wp[7].y, v.y);
    v.z = fmaf(z1.w, wp[7].z, v.z); v.w = fmaf(z1.w, wp[7].w, v.w);
    ((float4*)(out + ((size_t)blockIdx.x * 32 + row) * 256))[lane] = v;
  }
}

// ---------------- host launch ----------------
extern "C" void kernel_launch(void* const* d_in, const int* in_sizes, int n_in,
                              void* d_out, int out_size, void* d_ws, size_t ws_size,
                              hipStream_t stream) {
  const float* x     = (const float*)d_in[0];  // (16,1024,256)
  const float* adj   = (const float*)d_in[1];  // (1024,1024)
  const float* Wg    = (const float*)d_in[2];  // (256,256)
  const float* bg    = (const float*)d_in[3];  // (256,)
  const float* Wpre  = (const float*)d_in[4];  // (8,256)
  const float* bpre  = (const float*)d_in[5];  // (8,)
  const float* qw    = (const float*)d_in[6];  // (2,8)
  const float* Wpost = (const float*)d_in[7];  // (256,8)
  const float* bpost = (const float*)d_in[8];  // (256,)
  float* out = (float*)d_out;                  // (16,1024,256)

  char* ws = (char*)d_ws;
  unsigned short* adj_bf  = (unsigned short*)(ws + 0);          // 2 MiB
  unsigned short* Wg_bf   = (unsigned short*)(ws + 2097152);    // 128 KiB
  unsigned short* xagg_bf = (unsigned short*)(ws + 2228224);    // 8 MiB  (16384 x 256)
  unsigned short* xT_bf   = (unsigned short*)(ws + 10616832);   // 8 MiB  (16 x 256 x 1024)
  unsigned short* g_bf    = (unsigned short*)(ws + 19005440);   // 8 MiB  (16384 x 256)
  unsigned short* Uri     = (unsigned short*)(ws + 27394048);   // 256 KiB (512 x 256)

  // 1) prep: adj/Wg cvt + U-builder + x transpose
  prep_kernel<<<5248, 256, 0, stream>>>(adj, adj_bf, Wg, Wg_bf, qw, Uri, x, xT_bf);

  // 2) x_agg[b] = adj @ x[b] -> bf16
  gemm_bt_kernel<0><<<512, 256, 0, stream>>>(adj_bf, xT_bf, xagg_bf, nullptr,
                                             1024, 8, 4,
                                             0LL, 262144LL, 262144LL, 256);

  // 3) g = gelu(x_agg @ Wg^T + bg) -> bf16
  gemm_bt_kernel<1><<<512, 256, 0, stream>>>(xagg_bf, Wg_bf, g_bf, bg,
                                             256, 128, 4,
                                             0LL, 0LL, 0LL, 256);

  // 4) fused P0-build + S-GEMM (no-barrier K-loop) + measurement + projection
  qgemm_kernel<<<512, 512, 0, stream>>>(g_bf, Uri, Wpre, bpre, Wpost, bpost, out);
}